// Round 7
// baseline (216.132 us; speedup 1.0000x reference)
//
#include <hip/hip_runtime.h>
#include <math.h>

// Problem constants (fixed by setup_inputs in the reference)
constexpr int B_ = 2, C_ = 64, H_ = 180, W_ = 360;
constexpr int HW = H_ * W_;             // 64800
constexpr int Hp = H_ + 2, Wp = W_ + 2; // padded dims 182 x 362
constexpr int O_ = 2 * C_;              // 128 velocity outputs

// 4-byte-aligned float4 (taps are 4 contiguous floats at dword alignment)
typedef float float4a __attribute__((ext_vector_type(4), aligned(4)));

// NOTE (round-5 lesson): the reference's seam mapping is DISCONTINUOUS in lon
// (remainder wraps + clamped 1-px-pad bicubic). Coordinate math must stay
// bit-close to fp32 libm: asinf/atan2f/exact-division remainder only.
__device__ __forceinline__ float frem(float x, float y) {
    return x - floorf(x / y) * y;            // IEEE division, matches jnp
}
// remainder(x, 2): x*0.5f is EXACT (pow2), floor identical to floor(x/2).
__device__ __forceinline__ float frem2(float x) {
    return x - floorf(x * 0.5f) * 2.0f;
}

// bicubic weights, A = -0.75
__device__ __forceinline__ float cub1(float x) {   // |t| <= 1
    return (1.25f * x - 2.25f) * x * x + 1.0f;
}
__device__ __forceinline__ float cub2(float x) {   // 1 < |t| < 2
    return ((-0.75f * x + 3.75f) * x - 6.0f) * x + 3.0f;
}

// Read geo_cyclic_pad(hidden,1)[y][x] directly from the unpadded image.
__device__ __forceinline__ float fetch_pad(const float* __restrict__ img, int y, int x) {
    int wc = x - 1;
    if (x == 0)      wc = W_ - 1;
    if (x == Wp - 1) wc = 0;
    int hh = y - 1;
    bool top = (y == 0), bot = (y == Hp - 1);
    if (top) hh = 0;
    if (bot) hh = H_ - 1;
    if (top || bot) { wc += W_ / 2; if (wc >= W_) wc -= W_; }
    return img[hh * W_ + wc];
}

struct Coord { float tx, ty; int jx, jy; };

// Departure point -> padded-image bicubic coordinates (EXACT r11 sequence).
__device__ __forceinline__ Coord compute_coord(
    float u, float v, float dt, float sp, float cp, float lon_p,
    float min_lat, float min_lon, float inv_dlat, float inv_dlon)
{
    const float two_pi = 6.28318530717958647f;
    const float sxw = (float)W_ / (float)Wp;
    const float syh = (float)H_ / (float)Hp;

    const float lon_pr = -u * dt;
    const float lat_pr = -v * dt;
    float slp, clp, slo, clo;
    __sincosf(lat_pr, &slp, &clp);
    __sincosf(lon_pr, &slo, &clo);
    float sin_lat = slp * cp + clp * clo * sp;
    sin_lat = fminf(fmaxf(sin_lat, -1.0f + 1e-7f), 1.0f - 1e-7f);
    const float lat = asinf(sin_lat);
    const float num = clp * slo;
    const float den = clp * clo * cp - slp * sp;
    const float lon = frem(lon_p + atan2f(num, den) + two_pi, two_pi);

    float gx = (lon - min_lon) * inv_dlon - 1.0f;
    float gy = (lat - min_lat) * inv_dlat - 1.0f;
    gx = frem2(gx + 1.0f) - 1.0f;
    const bool left  = (gx <= 0.0f);
    const bool outer = (fabsf(gy) > 1.0f);
    if (outer) gx += left ? 1.0f : -1.0f;
    if (gy < -1.0f)     gy = -(2.0f + gy);
    else if (gy > 1.0f) gy = 2.0f - gy;
    gx *= sxw;
    gy *= syh;

    const float ix = (gx + 1.0f) * 0.5f * (float)(Wp - 1);
    const float iy = (gy + 1.0f) * 0.5f * (float)(Hp - 1);
    const float fx0 = floorf(ix), fy0 = floorf(iy);
    Coord cr;
    cr.tx = ix - fx0; cr.ty = iy - fy0;
    cr.jx = (int)fx0; cr.jy = (int)fy0;
    return cr;
}

__device__ __forceinline__ bool is_interior(const Coord& cr) {
    return (cr.jx >= 2) & (cr.jx <= Wp - 4) & (cr.jy >= 2) & (cr.jy <= Hp - 4);
}

// Weighted reduce of 16 taps held in t[16].
__device__ __forceinline__ float bicubic_reduce(const float* t, float tx, float ty) {
    const float wx0 = cub2(tx + 1.0f), wx1 = cub1(tx);
    const float wx2 = cub1(1.0f - tx), wx3 = cub2(2.0f - tx);
    const float wy0 = cub2(ty + 1.0f), wy1 = cub1(ty);
    const float wy2 = cub1(1.0f - ty), wy3 = cub2(2.0f - ty);
    const float r0 = fmaf(wx3, t[3],  fmaf(wx2, t[2],  fmaf(wx1, t[1],  wx0 * t[0])));
    const float r1 = fmaf(wx3, t[7],  fmaf(wx2, t[6],  fmaf(wx1, t[5],  wx0 * t[4])));
    const float r2 = fmaf(wx3, t[11], fmaf(wx2, t[10], fmaf(wx1, t[9],  wx0 * t[8])));
    const float r3 = fmaf(wx3, t[15], fmaf(wx2, t[14], fmaf(wx1, t[13], wx0 * t[12])));
    return fmaf(wy3, r3, fmaf(wy2, r2, fmaf(wy1, r1, wy0 * r0)));
}

__device__ __forceinline__ void taps_interior(const float* __restrict__ img,
                                              const Coord& cr, float* t) {
    const float* __restrict__ p = img + (cr.jy - 2) * W_ + (cr.jx - 2);
#pragma unroll
    for (int r = 0; r < 4; ++r) {
        const float4a row = *(const float4a*)(p + r * W_);
        t[r * 4 + 0] = row.x; t[r * 4 + 1] = row.y;
        t[r * 4 + 2] = row.z; t[r * 4 + 3] = row.w;
    }
}

__device__ __forceinline__ void taps_border(const float* __restrict__ img,
                                            const Coord& cr, float* t) {
    int xs[4], ys[4];
#pragma unroll
    for (int r = 0; r < 4; ++r) {
        xs[r] = min(max(cr.jx - 1 + r, 0), Wp - 1);
        ys[r] = min(max(cr.jy - 1 + r, 0), Hp - 1);
    }
#pragma unroll
    for (int r = 0; r < 4; ++r)
#pragma unroll
        for (int cc = 0; cc < 4; ++cc)
            t[r * 4 + cc] = fetch_pad(img, ys[r], xs[cc]);
}

// Coord + tap-issue for one element (used by the pipelined advect kernel).
__device__ __forceinline__ Coord coord_and_taps(
    const float* __restrict__ img, float u, float v, float dt,
    float sp, float cp, float lon_p,
    float min_lat, float min_lon, float inv_dlat, float inv_dlon, float* t)
{
    const Coord cr = compute_coord(u, v, dt, sp, cp, lon_p,
                                   min_lat, min_lon, inv_dlat, inv_dlon);
    if (__all(is_interior(cr))) taps_interior(img, cr, t);
    else                        taps_border(img, cr, t);
    return cr;
}

// Single-channel advect (used by fallback).
__device__ __forceinline__ float advect_one(
    const float* __restrict__ img, float u, float v, float dt,
    float sp, float cp, float lon_p,
    float min_lat, float min_lon, float inv_dlat, float inv_dlon)
{
    float t[16];
    const Coord cr = coord_and_taps(img, u, v, dt, sp, cp, lon_p,
                                    min_lat, min_lon, inv_dlat, inv_dlon, t);
    return bicubic_reduce(t, cr.tx, cr.ty);
}

// ---------------- Phase 1: uv = hidden x W_vel^T + b  (B,128,HW) ----------------
// Round-6 verified: this structure (256-thr, bounds(256,4), OG=2, acc[64] in
// regs, XCD-adjacent id remap) reproduces the baseline (~50 us back-solved).
// Keep byte-identical; do not touch.
constexpr int P1_PXT = 256;
constexpr int P1_OG  = 2;
constexpr int P1_OPG = O_ / P1_OG;      // 64 outputs per group
constexpr int P1_TILES = (HW + P1_PXT - 1) / P1_PXT; // 254
constexpr int P1_NXCD = 8;
constexpr int P1_TPX  = 32;             // tiles per XCD (8*32=256 >= 254)

__global__ __launch_bounds__(P1_PXT, 4) void nsl_vel(
    const float* __restrict__ hidden, const float* __restrict__ W_vel,
    const float* __restrict__ b_vel, float* __restrict__ uv)
{
    const int id   = blockIdx.x;
    const int xcd  = id & (P1_NXCD - 1);
    const int slot = id >> 3;                 // 0..127
    const int ogb  = slot & 3;                // 0..3 (fastest -> adjacent)
    const int lt   = slot >> 2;               // 0..31
    const int og   = ogb >> 1;                // 0..1
    const int b    = ogb & 1;                 // 0..1
    const int tile = xcd * P1_TPX + lt;
    if (tile >= P1_TILES) return;
    const int px   = tile * P1_PXT + threadIdx.x;
    if (px >= HW) return;

    float acc[P1_OPG];
#pragma unroll
    for (int j = 0; j < P1_OPG; ++j) acc[j] = b_vel[og * P1_OPG + j];

    const float* hb = hidden + (size_t)b * C_ * HW + px;
    const float* Wg = W_vel + (size_t)og * P1_OPG * C_;

    float xf[4];
#pragma unroll
    for (int t = 0; t < 4; ++t) xf[t] = hb[(size_t)t * HW];

    for (int k0 = 0; k0 < C_; k0 += 4) {
        float xc[4];
#pragma unroll
        for (int t = 0; t < 4; ++t) xc[t] = xf[t];
        if (k0 + 4 < C_) {
#pragma unroll
            for (int t = 0; t < 4; ++t) xf[t] = hb[(size_t)(k0 + 4 + t) * HW];
        }
        // k-chain per output stays ascending -> bitwise-identical uv.
#pragma unroll
        for (int j = 0; j < P1_OPG; ++j) {
            const float* wr = Wg + (size_t)j * C_ + k0;
            acc[j] = fmaf(wr[0], xc[0], acc[j]);
            acc[j] = fmaf(wr[1], xc[1], acc[j]);
            acc[j] = fmaf(wr[2], xc[2], acc[j]);
            acc[j] = fmaf(wr[3], xc[3], acc[j]);
        }
    }

    float* o = uv + ((size_t)b * O_ + og * P1_OPG) * HW + px;
#pragma unroll
    for (int j = 0; j < P1_OPG; ++j) o[(size_t)j * HW] = acc[j];
}

// ---------------- Phase 2: 2-element software-pipelined advect ----------------
// Round-6 analysis: advect is one-shot/thread -> ~1300cy serial chain hidden
// only by TLP; 66% VALUBusy = ~31 us of unhidden stall at VGPR 24 (huge reg
// headroom). Round-1 lesson: the compiler's pressure-aware scheduler will
// re-serialize two parallel chains on its own. Fix: PIN a 2-element pipeline
// with sched_barrier(0):
//   [coord(e0) + issue taps(e0)] || [coord(e1) + issue taps(e1)] || [reduce both]
// taps(e0) latency is covered by e1's ~150-inst coord chain BY CONSTRUCTION.
// Elements = rows ly and ly+8 of the same 16x16 bc tile (same img base ->
// gather locality; wave-uniform tail bands). Per-element op sequence is
// IDENTICAL to advect_one -> bitwise-identical output.
// bounds(128,6): ~85 VGPR cap so t0+t1 (32 regs) can stay live.
constexpr int P2_TX = 16, P2_TY = 16;                 // block pixel tile
constexpr int P2_GX = (W_ + P2_TX - 1) / P2_TX;       // 23
constexpr int P2_GY = (H_ + P2_TY - 1) / P2_TY;       // 12
constexpr int P2_NTILE = P2_GX * P2_GY;               // 276
constexpr int NXCD = 8;
constexpr int BC_PER_XCD = (B_ * C_) / NXCD;          // 16

__global__ __launch_bounds__(128, 6) void nsl_advect_p2(
    const float* __restrict__ hidden,    // (B,C,H,W)
    const float* __restrict__ lat_grid,  // (B,H,W)
    const float* __restrict__ lon_grid,  // (B,H,W)
    const float* __restrict__ uv,        // (B,128,HW) from phase 1
    const float* __restrict__ dt_p,
    float* __restrict__ out)             // (B,C,H,W)
{
    // blockIdx -> (xcd, bc, tile): same XCD-localized mapping as r13 (all 276
    // tiles of a bc on ONE XCD).
    const int id   = blockIdx.x;
    const int xcd  = id & (NXCD - 1);
    const int slot = id >> 3;                     // 0 .. 16*276-1
    const int bcl  = slot / P2_NTILE;             // 0..15 (block-uniform)
    const int tile = slot - bcl * P2_NTILE;       // 0..275
    const int bc   = xcd * BC_PER_XCD + bcl;      // b*C + c
    const int txx  = tile % P2_GX;
    const int tyy  = tile / P2_GX;

    const int lane = threadIdx.x & 63;
    const int wv   = threadIdx.x >> 6;            // 0..1 (128-thread block)
    const int lx   = lane & 15;
    const int ly   = (lane >> 4) + wv * 4;        // 0..7 (16x4 wave patch)
    const int px   = txx * P2_TX + lx;
    const int py0  = tyy * P2_TY + ly;            // element 0: rows 0..7
    const int py1  = py0 + 8;                     // element 1: rows 8..15
    if (px >= W_ || py0 >= H_) return;
    const bool e1ok = (py1 < H_);                 // wave-uniform (4-row bands)
    const int pix0 = py0 * W_ + px;
    const int pix1 = pix0 + 8 * W_;

    const int b  = bc >> 6;             // / C_
    const int c  = bc & (C_ - 1);

    const float dt      = dt_p[0];
    const float min_lat = lat_grid[0];
    const float max_lat = lat_grid[(H_ - 1) * W_];
    const float min_lon = lon_grid[0];
    const float max_lon = lon_grid[W_ - 1];
    const float inv_dlat = 2.0f / (max_lat - min_lat);
    const float inv_dlon = 2.0f / (max_lon - min_lon);

    // Issue ALL per-element global loads up front (both elements).
    const float lat0 = lat_grid[(size_t)b * HW + pix0];
    const float lon0 = lon_grid[(size_t)b * HW + pix0];
    const float u0 = uv[((size_t)b * O_ + c) * HW + pix0];
    const float v0 = uv[((size_t)b * O_ + C_ + c) * HW + pix0];
    float lat1 = 0.0f, lon1 = 0.0f, u1 = 0.0f, v1 = 0.0f;
    if (e1ok) {
        lat1 = lat_grid[(size_t)b * HW + pix1];
        lon1 = lon_grid[(size_t)b * HW + pix1];
        u1 = uv[((size_t)b * O_ + c) * HW + pix1];
        v1 = uv[((size_t)b * O_ + C_ + c) * HW + pix1];
    }

    const float* __restrict__ img = hidden + (size_t)bc * HW;

    // ---- Region A: element-0 coord chain + tap ISSUE ----
    float sp0, cp0;
    __sincosf(lat0, &sp0, &cp0);
    float t0[16];
    const Coord cr0 = coord_and_taps(img, u0, v0, dt, sp0, cp0, lon0,
                                     min_lat, min_lon, inv_dlat, inv_dlon, t0);
    __builtin_amdgcn_sched_barrier(0);   // nothing crosses: taps0 stay issued

    // ---- Region B: element-1 coord chain (covers taps0 latency) + tap issue ----
    float t1[16];
    Coord cr1; cr1.tx = 0.0f; cr1.ty = 0.0f; cr1.jx = 2; cr1.jy = 2;
    if (e1ok) {
        float sp1, cp1;
        __sincosf(lat1, &sp1, &cp1);
        cr1 = coord_and_taps(img, u1, v1, dt, sp1, cp1, lon1,
                             min_lat, min_lon, inv_dlat, inv_dlon, t1);
    }
    __builtin_amdgcn_sched_barrier(0);

    // ---- Region C: reduces + stores ----
    out[(size_t)bc * HW + pix0] = bicubic_reduce(t0, cr0.tx, cr0.ty);
    if (e1ok)
        out[(size_t)bc * HW + pix1] = bicubic_reduce(t1, cr1.tx, cr1.ty);
}

// ---------------- Fallback: fused kernel (round-6 structure, passing) ----------------
constexpr int FB_CG = 4, FB_CPT = C_ / FB_CG, FB_PXT = 256;
constexpr int FB_TILES = (HW + FB_PXT - 1) / FB_PXT;

__global__ __launch_bounds__(FB_PXT, 6) void nsl_fused(
    const float* __restrict__ hidden, const float* __restrict__ lat_grid,
    const float* __restrict__ lon_grid, const float* __restrict__ W_vel,
    const float* __restrict__ b_vel, const float* __restrict__ dt_p,
    float* __restrict__ out)
{
    const int bid  = blockIdx.x;
    const int tile = bid % FB_TILES;
    const int cg   = (bid / FB_TILES) % FB_CG;
    const int b    = bid / (FB_TILES * FB_CG);
    const int px   = tile * FB_PXT + threadIdx.x;
    if (px >= HW) return;

    const float dt      = dt_p[0];
    const float min_lat = lat_grid[0];
    const float max_lat = lat_grid[(H_ - 1) * W_];
    const float min_lon = lon_grid[0];
    const float max_lon = lon_grid[W_ - 1];
    const float inv_dlat = 2.0f / (max_lat - min_lat);
    const float inv_dlon = 2.0f / (max_lon - min_lon);

    const float lat_p = lat_grid[(size_t)b * HW + px];
    const float lon_p = lon_grid[(size_t)b * HW + px];
    float sp, cp;
    __sincosf(lat_p, &sp, &cp);

    float u[FB_CPT], v[FB_CPT];
#pragma unroll
    for (int i = 0; i < FB_CPT; ++i) {
        u[i] = b_vel[cg * FB_CPT + i];
        v[i] = b_vel[C_ + cg * FB_CPT + i];
    }
    const float* hb = hidden + (size_t)b * C_ * HW + px;
#pragma unroll 2
    for (int k = 0; k < C_; ++k) {
        const float x = hb[(size_t)k * HW];
#pragma unroll
        for (int i = 0; i < FB_CPT; ++i) {
            u[i] = fmaf(W_vel[(size_t)(cg * FB_CPT + i) * C_ + k], x, u[i]);
            v[i] = fmaf(W_vel[(size_t)(C_ + cg * FB_CPT + i) * C_ + k], x, v[i]);
        }
    }

    for (int i = 0; i < FB_CPT; ++i) {
        const int c = cg * FB_CPT + i;
        const float* __restrict__ img = hidden + ((size_t)b * C_ + c) * HW;
        out[((size_t)b * C_ + c) * HW + px] =
            advect_one(img, u[i], v[i], dt, sp, cp, lon_p,
                       min_lat, min_lon, inv_dlat, inv_dlon);
    }
}

extern "C" void kernel_launch(void* const* d_in, const int* in_sizes, int n_in,
                              void* d_out, int out_size, void* d_ws, size_t ws_size,
                              hipStream_t stream) {
    const float* hidden   = (const float*)d_in[0];
    const float* lat_grid = (const float*)d_in[1];
    const float* lon_grid = (const float*)d_in[2];
    const float* W_vel    = (const float*)d_in[3];
    const float* b_vel    = (const float*)d_in[4];
    const float* dt_p     = (const float*)d_in[5];
    float* out = (float*)d_out;

    const size_t uv_bytes = (size_t)B_ * O_ * HW * sizeof(float); // 66.4 MB
    if (ws_size >= uv_bytes) {
        float* uv = (float*)d_ws;
        const int grid1 = P1_NXCD * P1_TPX * P1_OG * B_;  // 1024 (254 live tiles x4)
        nsl_vel<<<grid1, P1_PXT, 0, stream>>>(hidden, W_vel, b_vel, uv);
        const int grid2 = NXCD * BC_PER_XCD * P2_NTILE;   // 35328 blocks x 128 thr
        nsl_advect_p2<<<grid2, 128, 0, stream>>>(
            hidden, lat_grid, lon_grid, uv, dt_p, out);
    } else {
        nsl_fused<<<B_ * FB_CG * FB_TILES, FB_PXT, 0, stream>>>(
            hidden, lat_grid, lon_grid, W_vel, b_vel, dt_p, out);
    }
}

// Round 8
// 206.483 us; speedup vs baseline: 1.0467x; 1.0467x over previous
//
#include <hip/hip_runtime.h>
#include <math.h>

// Problem constants (fixed by setup_inputs in the reference)
constexpr int B_ = 2, C_ = 64, H_ = 180, W_ = 360;
constexpr int HW = H_ * W_;             // 64800
constexpr int Hp = H_ + 2, Wp = W_ + 2; // padded dims 182 x 362
constexpr int O_ = 2 * C_;              // 128 velocity outputs

// 4-byte-aligned float4 (taps are 4 contiguous floats at dword alignment)
typedef float float4a __attribute__((ext_vector_type(4), aligned(4)));

// SESSION FLOOR (8 experiments, rounds 0-7 of this session):
//  - advect: r13 structure, 92.3 us, VGPR 24, VALUBusy ~66%. Semantically
//    locked coord chain (~578 wave-insts/elem of exact libm); 2-ch ILP,
//    fenced 2-elem pipeline, and fusion ALL regressed (compiler re-serializes
//    parallel chains; sched_barrier fences cost more than overlap gains).
//  - vel: round-0 structure (256thr/(256,4)/OG=2/acc[64]) ~50 us; OG=4,
//    LDS-staged, and 128-thr variants all regressed (x re-read / spill).
//  - fusion: FETCH 290 MB (8.7x hidden re-read from HBM) -> dominated.
//  - harness-fixed overhead ~64 us; inter-dispatch gap < 1 us.
// Do not restructure without new counter evidence.

// NOTE (round-5 lesson, prev session): the reference's seam mapping is
// DISCONTINUOUS in lon (remainder wraps + clamped 1-px-pad bicubic).
// Coordinate math must stay bit-close to fp32 libm: asinf/atan2f/
// exact-division remainder only.
__device__ __forceinline__ float frem(float x, float y) {
    return x - floorf(x / y) * y;            // IEEE division, matches jnp
}
// remainder(x, 2): x*0.5f is EXACT (pow2), floor identical to floor(x/2).
__device__ __forceinline__ float frem2(float x) {
    return x - floorf(x * 0.5f) * 2.0f;
}

// bicubic weights, A = -0.75
__device__ __forceinline__ float cub1(float x) {   // |t| <= 1
    return (1.25f * x - 2.25f) * x * x + 1.0f;
}
__device__ __forceinline__ float cub2(float x) {   // 1 < |t| < 2
    return ((-0.75f * x + 3.75f) * x - 6.0f) * x + 3.0f;
}

// Read geo_cyclic_pad(hidden,1)[y][x] directly from the unpadded image.
__device__ __forceinline__ float fetch_pad(const float* __restrict__ img, int y, int x) {
    int wc = x - 1;
    if (x == 0)      wc = W_ - 1;
    if (x == Wp - 1) wc = 0;
    int hh = y - 1;
    bool top = (y == 0), bot = (y == Hp - 1);
    if (top) hh = 0;
    if (bot) hh = H_ - 1;
    if (top || bot) { wc += W_ / 2; if (wc >= W_) wc -= W_; }
    return img[hh * W_ + wc];
}

struct Coord { float tx, ty; int jx, jy; };

// Departure point -> padded-image bicubic coordinates (EXACT r11 sequence).
__device__ __forceinline__ Coord compute_coord(
    float u, float v, float dt, float sp, float cp, float lon_p,
    float min_lat, float min_lon, float inv_dlat, float inv_dlon)
{
    const float two_pi = 6.28318530717958647f;
    const float sxw = (float)W_ / (float)Wp;
    const float syh = (float)H_ / (float)Hp;

    const float lon_pr = -u * dt;
    const float lat_pr = -v * dt;
    float slp, clp, slo, clo;
    __sincosf(lat_pr, &slp, &clp);
    __sincosf(lon_pr, &slo, &clo);
    float sin_lat = slp * cp + clp * clo * sp;
    sin_lat = fminf(fmaxf(sin_lat, -1.0f + 1e-7f), 1.0f - 1e-7f);
    const float lat = asinf(sin_lat);
    const float num = clp * slo;
    const float den = clp * clo * cp - slp * sp;
    const float lon = frem(lon_p + atan2f(num, den) + two_pi, two_pi);

    float gx = (lon - min_lon) * inv_dlon - 1.0f;
    float gy = (lat - min_lat) * inv_dlat - 1.0f;
    gx = frem2(gx + 1.0f) - 1.0f;
    const bool left  = (gx <= 0.0f);
    const bool outer = (fabsf(gy) > 1.0f);
    if (outer) gx += left ? 1.0f : -1.0f;
    if (gy < -1.0f)     gy = -(2.0f + gy);
    else if (gy > 1.0f) gy = 2.0f - gy;
    gx *= sxw;
    gy *= syh;

    const float ix = (gx + 1.0f) * 0.5f * (float)(Wp - 1);
    const float iy = (gy + 1.0f) * 0.5f * (float)(Hp - 1);
    const float fx0 = floorf(ix), fy0 = floorf(iy);
    Coord cr;
    cr.tx = ix - fx0; cr.ty = iy - fy0;
    cr.jx = (int)fx0; cr.jy = (int)fy0;
    return cr;
}

__device__ __forceinline__ bool is_interior(const Coord& cr) {
    return (cr.jx >= 2) & (cr.jx <= Wp - 4) & (cr.jy >= 2) & (cr.jy <= Hp - 4);
}

// Weighted reduce of 16 taps held in t[16].
__device__ __forceinline__ float bicubic_reduce(const float* t, float tx, float ty) {
    const float wx0 = cub2(tx + 1.0f), wx1 = cub1(tx);
    const float wx2 = cub1(1.0f - tx), wx3 = cub2(2.0f - tx);
    const float wy0 = cub2(ty + 1.0f), wy1 = cub1(ty);
    const float wy2 = cub1(1.0f - ty), wy3 = cub2(2.0f - ty);
    const float r0 = fmaf(wx3, t[3],  fmaf(wx2, t[2],  fmaf(wx1, t[1],  wx0 * t[0])));
    const float r1 = fmaf(wx3, t[7],  fmaf(wx2, t[6],  fmaf(wx1, t[5],  wx0 * t[4])));
    const float r2 = fmaf(wx3, t[11], fmaf(wx2, t[10], fmaf(wx1, t[9],  wx0 * t[8])));
    const float r3 = fmaf(wx3, t[15], fmaf(wx2, t[14], fmaf(wx1, t[13], wx0 * t[12])));
    return fmaf(wy3, r3, fmaf(wy2, r2, fmaf(wy1, r1, wy0 * r0)));
}

__device__ __forceinline__ void taps_interior(const float* __restrict__ img,
                                              const Coord& cr, float* t) {
    const float* __restrict__ p = img + (cr.jy - 2) * W_ + (cr.jx - 2);
#pragma unroll
    for (int r = 0; r < 4; ++r) {
        const float4a row = *(const float4a*)(p + r * W_);
        t[r * 4 + 0] = row.x; t[r * 4 + 1] = row.y;
        t[r * 4 + 2] = row.z; t[r * 4 + 3] = row.w;
    }
}

__device__ __forceinline__ void taps_border(const float* __restrict__ img,
                                            const Coord& cr, float* t) {
    int xs[4], ys[4];
#pragma unroll
    for (int r = 0; r < 4; ++r) {
        xs[r] = min(max(cr.jx - 1 + r, 0), Wp - 1);
        ys[r] = min(max(cr.jy - 1 + r, 0), Hp - 1);
    }
#pragma unroll
    for (int r = 0; r < 4; ++r)
#pragma unroll
        for (int cc = 0; cc < 4; ++cc)
            t[r * 4 + cc] = fetch_pad(img, ys[r], xs[cc]);
}

// Single-channel advect (used by 2D kernel and fallback).
__device__ __forceinline__ float advect_one(
    const float* __restrict__ img, float u, float v, float dt,
    float sp, float cp, float lon_p,
    float min_lat, float min_lon, float inv_dlat, float inv_dlon)
{
    const Coord cr = compute_coord(u, v, dt, sp, cp, lon_p,
                                   min_lat, min_lon, inv_dlat, inv_dlon);
    float t[16];
    if (__all(is_interior(cr))) taps_interior(img, cr, t);
    else                        taps_border(img, cr, t);
    return bicubic_reduce(t, cr.tx, cr.ty);
}

// ---------------- Phase 1: uv = hidden x W_vel^T + b  (B,128,HW) ----------------
// Round-6 verified: this structure (256-thr, bounds(256,4), OG=2, acc[64] in
// regs, XCD-adjacent id remap) reproduces the baseline (~50 us back-solved).
constexpr int P1_PXT = 256;
constexpr int P1_OG  = 2;
constexpr int P1_OPG = O_ / P1_OG;      // 64 outputs per group
constexpr int P1_TILES = (HW + P1_PXT - 1) / P1_PXT; // 254
constexpr int P1_NXCD = 8;
constexpr int P1_TPX  = 32;             // tiles per XCD (8*32=256 >= 254)

__global__ __launch_bounds__(P1_PXT, 4) void nsl_vel(
    const float* __restrict__ hidden, const float* __restrict__ W_vel,
    const float* __restrict__ b_vel, float* __restrict__ uv)
{
    const int id   = blockIdx.x;
    const int xcd  = id & (P1_NXCD - 1);
    const int slot = id >> 3;                 // 0..127
    const int ogb  = slot & 3;                // 0..3 (fastest -> adjacent)
    const int lt   = slot >> 2;               // 0..31
    const int og   = ogb >> 1;                // 0..1
    const int b    = ogb & 1;                 // 0..1
    const int tile = xcd * P1_TPX + lt;
    if (tile >= P1_TILES) return;
    const int px   = tile * P1_PXT + threadIdx.x;
    if (px >= HW) return;

    float acc[P1_OPG];
#pragma unroll
    for (int j = 0; j < P1_OPG; ++j) acc[j] = b_vel[og * P1_OPG + j];

    const float* hb = hidden + (size_t)b * C_ * HW + px;
    const float* Wg = W_vel + (size_t)og * P1_OPG * C_;

    float xf[4];
#pragma unroll
    for (int t = 0; t < 4; ++t) xf[t] = hb[(size_t)t * HW];

    for (int k0 = 0; k0 < C_; k0 += 4) {
        float xc[4];
#pragma unroll
        for (int t = 0; t < 4; ++t) xc[t] = xf[t];
        if (k0 + 4 < C_) {
#pragma unroll
            for (int t = 0; t < 4; ++t) xf[t] = hb[(size_t)(k0 + 4 + t) * HW];
        }
        // k-chain per output stays ascending -> bitwise-identical uv.
#pragma unroll
        for (int j = 0; j < P1_OPG; ++j) {
            const float* wr = Wg + (size_t)j * C_ + k0;
            acc[j] = fmaf(wr[0], xc[0], acc[j]);
            acc[j] = fmaf(wr[1], xc[1], acc[j]);
            acc[j] = fmaf(wr[2], xc[2], acc[j]);
            acc[j] = fmaf(wr[3], xc[3], acc[j]);
        }
    }

    float* o = uv + ((size_t)b * O_ + og * P1_OPG) * HW + px;
#pragma unroll
    for (int j = 0; j < P1_OPG; ++j) o[(size_t)j * HW] = acc[j];
}

// ---------------- Phase 2: XCD-localized 16x16 tiles, 16x4 wave patches --------
// r13-proven structure: single channel per thread, VGPR 24, ~66% VALUBusy
// @ ~92.3 us. All 276 tiles of a bc on ONE XCD. Near its op-count floor
// (~578 issued VALU wave-insts/element, exact-libm semantics) -- locked.
constexpr int P2_TX = 16, P2_TY = 16;                 // block pixel tile
constexpr int P2_GX = (W_ + P2_TX - 1) / P2_TX;       // 23
constexpr int P2_GY = (H_ + P2_TY - 1) / P2_TY;       // 12
constexpr int P2_NTILE = P2_GX * P2_GY;               // 276
constexpr int NXCD = 8;
constexpr int BC_PER_XCD = (B_ * C_) / NXCD;          // 16

__global__ __launch_bounds__(256, 8) void nsl_advect_x(
    const float* __restrict__ hidden,    // (B,C,H,W)
    const float* __restrict__ lat_grid,  // (B,H,W)
    const float* __restrict__ lon_grid,  // (B,H,W)
    const float* __restrict__ uv,        // (B,128,HW) from phase 1
    const float* __restrict__ dt_p,
    float* __restrict__ out)             // (B,C,H,W)
{
    const int id   = blockIdx.x;
    const int xcd  = id & (NXCD - 1);
    const int slot = id >> 3;                     // 0 .. 16*276-1
    const int bcl  = slot / P2_NTILE;             // 0..15 (block-uniform)
    const int tile = slot - bcl * P2_NTILE;       // 0..275
    const int bc   = xcd * BC_PER_XCD + bcl;      // b*C + c
    const int txx  = tile % P2_GX;
    const int tyy  = tile / P2_GX;

    const int lane = threadIdx.x & 63;
    const int wv   = threadIdx.x >> 6;            // 0..3
    const int lx   = lane & 15;
    const int ly   = (lane >> 4) + wv * 4;        // wave = 16x4 patch (r13 win)
    const int px   = txx * P2_TX + lx;
    const int py   = tyy * P2_TY + ly;
    if (px >= W_ || py >= H_) return;
    const int pix  = py * W_ + px;

    const int b  = bc >> 6;             // / C_
    const int c  = bc & (C_ - 1);

    const float dt      = dt_p[0];
    const float min_lat = lat_grid[0];
    const float max_lat = lat_grid[(H_ - 1) * W_];
    const float min_lon = lon_grid[0];
    const float max_lon = lon_grid[W_ - 1];
    const float inv_dlat = 2.0f / (max_lat - min_lat);
    const float inv_dlon = 2.0f / (max_lon - min_lon);

    const float lat_p = lat_grid[(size_t)b * HW + pix];
    const float lon_p = lon_grid[(size_t)b * HW + pix];
    float sp, cp;
    __sincosf(lat_p, &sp, &cp);

    const float u = uv[((size_t)b * O_ + c) * HW + pix];
    const float v = uv[((size_t)b * O_ + C_ + c) * HW + pix];

    const float* __restrict__ img = hidden + (size_t)bc * HW;
    out[(size_t)bc * HW + pix] = advect_one(img, u, v, dt, sp, cp, lon_p,
                                            min_lat, min_lon, inv_dlat, inv_dlon);
}

// ---------------- Fallback: fused kernel (round-6 structure, passing) ----------------
constexpr int FB_CG = 4, FB_CPT = C_ / FB_CG, FB_PXT = 256;
constexpr int FB_TILES = (HW + FB_PXT - 1) / FB_PXT;

__global__ __launch_bounds__(FB_PXT, 6) void nsl_fused(
    const float* __restrict__ hidden, const float* __restrict__ lat_grid,
    const float* __restrict__ lon_grid, const float* __restrict__ W_vel,
    const float* __restrict__ b_vel, const float* __restrict__ dt_p,
    float* __restrict__ out)
{
    const int bid  = blockIdx.x;
    const int tile = bid % FB_TILES;
    const int cg   = (bid / FB_TILES) % FB_CG;
    const int b    = bid / (FB_TILES * FB_CG);
    const int px   = tile * FB_PXT + threadIdx.x;
    if (px >= HW) return;

    const float dt      = dt_p[0];
    const float min_lat = lat_grid[0];
    const float max_lat = lat_grid[(H_ - 1) * W_];
    const float min_lon = lon_grid[0];
    const float max_lon = lon_grid[W_ - 1];
    const float inv_dlat = 2.0f / (max_lat - min_lat);
    const float inv_dlon = 2.0f / (max_lon - min_lon);

    const float lat_p = lat_grid[(size_t)b * HW + px];
    const float lon_p = lon_grid[(size_t)b * HW + px];
    float sp, cp;
    __sincosf(lat_p, &sp, &cp);

    float u[FB_CPT], v[FB_CPT];
#pragma unroll
    for (int i = 0; i < FB_CPT; ++i) {
        u[i] = b_vel[cg * FB_CPT + i];
        v[i] = b_vel[C_ + cg * FB_CPT + i];
    }
    const float* hb = hidden + (size_t)b * C_ * HW + px;
#pragma unroll 2
    for (int k = 0; k < C_; ++k) {
        const float x = hb[(size_t)k * HW];
#pragma unroll
        for (int i = 0; i < FB_CPT; ++i) {
            u[i] = fmaf(W_vel[(size_t)(cg * FB_CPT + i) * C_ + k], x, u[i]);
            v[i] = fmaf(W_vel[(size_t)(C_ + cg * FB_CPT + i) * C_ + k], x, v[i]);
        }
    }

    for (int i = 0; i < FB_CPT; ++i) {
        const int c = cg * FB_CPT + i;
        const float* __restrict__ img = hidden + ((size_t)b * C_ + c) * HW;
        out[((size_t)b * C_ + c) * HW + px] =
            advect_one(img, u[i], v[i], dt, sp, cp, lon_p,
                       min_lat, min_lon, inv_dlat, inv_dlon);
    }
}

extern "C" void kernel_launch(void* const* d_in, const int* in_sizes, int n_in,
                              void* d_out, int out_size, void* d_ws, size_t ws_size,
                              hipStream_t stream) {
    const float* hidden   = (const float*)d_in[0];
    const float* lat_grid = (const float*)d_in[1];
    const float* lon_grid = (const float*)d_in[2];
    const float* W_vel    = (const float*)d_in[3];
    const float* b_vel    = (const float*)d_in[4];
    const float* dt_p     = (const float*)d_in[5];
    float* out = (float*)d_out;

    const size_t uv_bytes = (size_t)B_ * O_ * HW * sizeof(float); // 66.4 MB
    if (ws_size >= uv_bytes) {
        float* uv = (float*)d_ws;
        const int grid1 = P1_NXCD * P1_TPX * P1_OG * B_;  // 1024 (254 live tiles x4)
        nsl_vel<<<grid1, P1_PXT, 0, stream>>>(hidden, W_vel, b_vel, uv);
        const int grid2 = NXCD * BC_PER_XCD * P2_NTILE;   // 35328
        nsl_advect_x<<<grid2, 256, 0, stream>>>(
            hidden, lat_grid, lon_grid, uv, dt_p, out);
    } else {
        nsl_fused<<<B_ * FB_CG * FB_TILES, FB_PXT, 0, stream>>>(
            hidden, lat_grid, lon_grid, W_vel, b_vel, dt_p, out);
    }
}